// Round 5
// baseline (191.865 us; speedup 1.0000x reference)
//
#include <hip/hip_runtime.h>
#include <math.h>

#define MIN_T    0.01f
#define MAX_T    0.5f
#define LESION_T 0.3f

constexpr int NB       = 16;
constexpr int DIM      = 128;
constexpr int PLANE_F4 = DIM * DIM / 4;        // 4096 float4 per plane
constexpr int VOX      = DIM * DIM * DIM;      // 2,097,152
constexpr int THREADS  = 512;                  // 16 rows x 32 float4-cols
constexpr int ROWS     = 16;                   // rows of a plane per block
constexpr int HWBLKS   = DIM / ROWS;           // 8 row-slabs
constexpr int DSEGS    = 4;                    // d-axis segments
constexpr int DPS      = DIM / DSEGS;          // 32 planes per segment
constexpr int NACC     = 8;
constexpr int SLOTS_PER_B = DSEGS * HWBLKS;    // 32 partial slots per batch
constexpr int NWAVES   = THREADS / 64;         // 8
constexpr int NBLKS    = DSEGS * HWBLKS * NB;  // 512
constexpr int NXCD     = 8;
constexpr int CHUNK    = NBLKS / NXCD;         // 64 blocks (=2 batches) per XCD

// Per-slot accumulator layout (floats):
// 0: cnt(>MIN_T)  1: cnt(>MAX_T)  2: sum|d-diff|  3: sum|h-diff|
// 4: sum|w-diff|  5: sum s*mask   6: sum s^2*mask 7: cnt(>LESION_T)
//
// Structure notes (evidence, rounds 0-4):
//  - dual-load of row h+1 (vh) is an L1 hit for 15/16 rows; LDS plane-exchange
//    with per-plane barriers measured ~3-4us SLOWER (R1). Keep dual-load.
//  - forced 8 waves/SIMD + ballot counting REGRESSED (R3). Keep cndmask.
//  - 2-deep pipeline WON ~1.4us (R4): latency exposure is real -> go 3-deep.
//  - R5: XCD-chunk swizzle (bijective, 512%8==0): each XCD owns 2 whole
//    batches -> row-slab boundary refetch (1/16) and d-seg overlap planes
//    (+2.3%) become L2-local instead of cross-XCD HBM re-reads.
__global__ __launch_bounds__(THREADS)
void partial_kernel(const float* __restrict__ pred, float* __restrict__ ws)
{
    // bijective XCD swizzle: HW round-robins consecutive blockIdx across 8
    // XCDs; g gives XCD k the contiguous work chunk [k*CHUNK, (k+1)*CHUNK).
    const int bid = (int)blockIdx.x;
    const int g   = (bid & (NXCD - 1)) * CHUNK + (bid >> 3);
    const int b     = g >> 5;          // batch 0..15
    const int rem   = g & 31;
    const int hwblk = rem >> 2;        // row-slab 0..7
    const int seg   = rem & 3;         // d-segment 0..3

    const int tid   = (int)threadIdx.x;
    const int r     = tid >> 5;                // local row 0..15

    const int  h    = hwblk * ROWS + r;
    const bool do_h = (h < DIM - 1);           // h-pair (h,h+1) exists
    const bool do_w = ((tid & 31) != 31);      // w-cross pair exists

    const float4* __restrict__ s4 =
        reinterpret_cast<const float4*>(pred + (size_t)b * VOX);

    const int d0    = seg * DPS;
    const int d_end = (seg == DSEGS - 1) ? (DIM - 1) : (d0 + DPS);

    float cnt_min = 0.f, cnt_max = 0.f, sum_d = 0.f, sum_h = 0.f,
          sum_w = 0.f, sm = 0.f, sm2 = 0.f, les = 0.f;
    const float4 zero4 = { 0.f, 0.f, 0.f, 0.f };

    // element stats + w/h diffs for one float4 (its plane)
    auto process = [&](const float4& v, const float4& vh) {
        const float xs[4] = { v.x, v.y, v.z, v.w };
        #pragma unroll
        for (int j = 0; j < 4; ++j) {
            const float x  = xs[j];
            const float mk = (x > MIN_T) ? 1.0f : 0.0f;
            cnt_min += mk;
            cnt_max += (x > MAX_T)    ? 1.0f : 0.0f;
            les     += (x > LESION_T) ? 1.0f : 0.0f;
            sm      += x * mk;
            sm2     += x * x * mk;
        }
        sum_w += fabsf(v.y - v.x) + fabsf(v.z - v.y) + fabsf(v.w - v.z);
        const float nx = __shfl_down(v.x, 1, 64);   // next float4's .x (same row)
        if (do_w) sum_w += fabsf(nx - v.w);
        if (do_h) sum_h += fabsf(vh.x - v.x) + fabsf(vh.y - v.y)
                         + fabsf(vh.z - v.z) + fabsf(vh.w - v.w);
    };

    // thread owns float4 at (h, w4 = tid&31) on every plane.
    // 3-deep pipeline: A = plane d-1, B = d, C = d+1, prefetch D = d+2.
    size_t base = (size_t)d0 * PLANE_F4 + hwblk * THREADS + tid;

    float4 vA  = s4[base];
    float4 vAh = do_h ? s4[base + 32] : zero4;
    float4 vB  = s4[base + PLANE_F4];
    float4 vBh = do_h ? s4[base + PLANE_F4 + 32] : zero4;
    float4 vC  = s4[base + 2 * (size_t)PLANE_F4];
    float4 vCh = do_h ? s4[base + 2 * (size_t)PLANE_F4 + 32] : zero4;

    // pairs (d-1, d) for d in [d0+1, d_end]; stats for planes d0 .. d_end-1
    #pragma unroll 2
    for (int d = d0 + 1; d <= d_end; ++d) {
        float4 vD = zero4, vDh = zero4;
        if (d + 2 <= d_end) {                   // uniform branch; no OOB, no waste
            vD  = s4[base + 3 * (size_t)PLANE_F4];
            vDh = do_h ? s4[base + 3 * (size_t)PLANE_F4 + 32] : zero4;
        }
        process(vA, vAh);
        sum_d += fabsf(vB.x - vA.x) + fabsf(vB.y - vA.y)
               + fabsf(vB.z - vA.z) + fabsf(vB.w - vA.w);
        vA = vB; vAh = vBh;
        vB = vC; vBh = vCh;
        vC = vD; vCh = vDh;
        base += PLANE_F4;
    }
    if (seg == DSEGS - 1)       // plane 127's element stats (not a d-pair source)
        process(vA, vAh);

    // wave (64-lane) shuffle reduction, then LDS across 8 waves
    float vals[NACC] = { cnt_min, cnt_max, sum_d, sum_h, sum_w, sm, sm2, les };
    #pragma unroll
    for (int vi = 0; vi < NACC; ++vi) {
        float x = vals[vi];
        #pragma unroll
        for (int off = 32; off > 0; off >>= 1)
            x += __shfl_down(x, off, 64);
        vals[vi] = x;
    }

    __shared__ float red[NWAVES][NACC];
    const int wave = tid >> 6;
    const int lane = tid & 63;
    if (lane == 0) {
        #pragma unroll
        for (int vi = 0; vi < NACC; ++vi) red[wave][vi] = vals[vi];
    }
    __syncthreads();
    if (tid < NACC) {
        float t = 0.f;
        #pragma unroll
        for (int w = 0; w < NWAVES; ++w) t += red[w][tid];
        const int slot = b * SLOTS_PER_B + hwblk * DSEGS + seg;
        ws[(size_t)slot * NACC + tid] = t;   // distinct slot: no memset, no atomics
    }
}

__global__ __launch_bounds__(512)
void finalize_kernel(const float* __restrict__ ws, float* __restrict__ out)
{
    const int tid = (int)threadIdx.x;
    const int b   = tid >> 5;      // batch 0..15 (one 32-lane group per batch)
    const int k   = tid & 31;      // slot within batch

    double a[NACC];
    const float* p = ws + ((size_t)(b * SLOTS_PER_B + k)) * NACC;
    #pragma unroll
    for (int vi = 0; vi < NACC; ++vi) a[vi] = (double)p[vi];

    #pragma unroll
    for (int vi = 0; vi < NACC; ++vi) {
        #pragma unroll
        for (int off = 16; off > 0; off >>= 1)
            a[vi] += __shfl_down(a[vi], off, 32);
    }

    __shared__ double bl[NB];
    if (k == 0) {
        const double cnt    = a[0];
        const double cntmax = a[1];
        const double sd     = a[2];
        const double sh     = a[3];
        const double sw     = a[4];
        const double sm     = a[5];
        const double sm2    = a[6];
        const double les    = a[7];

        const double inv_vox = 1.0 / (double)VOX;
        const double act  = cnt    * inv_vox;
        const double high = cntmax * inv_vox;

        double loss = fmax(0.005 - act, 0.0) * 15.0      // W_MIN
                    + fmax(high - 0.03, 0.0) * 5.0;      // W_MAX

        const double grad_den = 127.0 * 128.0 * 128.0;   // diff-array size
        const double avg_grad = (sd + sh + sw) / (3.0 * grad_den);
        if (les > 0.5)
            loss += fmin(avg_grad, 1.0) * 5.0;           // W_CONT

        const double cnt_safe = fmax(cnt, 1.0);
        const double m  = sm / cnt_safe;
        double sq = sm2 - 2.0 * m * sm + m * m * cnt;
        if (sq < 0.0) sq = 0.0;

        const bool gate = (act > 0.001) && (cnt > 1.0);
        if (gate) {
            const double var     = sq / fmax(cnt - 1.0, 1.0);
            const double rel_std = sqrt(var) / (m + 1e-6);
            loss += exp(-5.0 * rel_std) * 7.0;           // W_SIZE
        }
        bl[b] = loss;
    }
    __syncthreads();
    if (tid == 0) {
        double s = 0.0;
        #pragma unroll
        for (int i = 0; i < NB; ++i) s += bl[i];
        out[0] = (float)(s / (double)NB);
    }
}

extern "C" void kernel_launch(void* const* d_in, const int* in_sizes, int n_in,
                              void* d_out, int out_size, void* d_ws, size_t ws_size,
                              hipStream_t stream)
{
    const float* pred = (const float*)d_in[0];
    float* out        = (float*)d_out;
    float* ws         = (float*)d_ws;

    partial_kernel<<<dim3(NBLKS), THREADS, 0, stream>>>(pred, ws);
    finalize_kernel<<<1, 512, 0, stream>>>(ws, out);
}

// Round 6
// 189.679 us; speedup vs baseline: 1.0115x; 1.0115x over previous
//
#include <hip/hip_runtime.h>
#include <math.h>

#define MIN_T    0.01f
#define MAX_T    0.5f
#define LESION_T 0.3f

constexpr int NB       = 16;
constexpr int DIM      = 128;
constexpr int PLANE_F4 = DIM * DIM / 4;        // 4096 float4 per plane
constexpr int VOX      = DIM * DIM * DIM;      // 2,097,152
constexpr int THREADS  = 512;                  // 16 rows x 32 float4-cols
constexpr int ROWS     = 16;                   // rows of a plane per block
constexpr int HWBLKS   = DIM / ROWS;           // 8 row-slabs
constexpr int DSEGS    = 4;                    // d-axis segments
constexpr int DPS      = DIM / DSEGS;          // 32 planes per segment
constexpr int NACC     = 8;
constexpr int SLOTS_PER_B = DSEGS * HWBLKS;    // 32 partial slots per batch
constexpr int NWAVES   = THREADS / 64;         // 8
constexpr int NBLKS    = DSEGS * HWBLKS * NB;  // 512
constexpr int NXCD     = 8;
constexpr int CHUNK    = NBLKS / NXCD;         // 64 blocks (=2 batches) per XCD

// Per-slot accumulator layout (floats):
// 0: cnt(>MIN_T)  1: cnt(>MAX_T)  2: sum|d-diff|  3: sum|h-diff|
// 4: sum|w-diff|  5: sum s*mask   6: sum s^2*mask 7: cnt(>LESION_T)
//
// Structure notes (evidence, rounds 0-5):
//  - dual-load of row h+1 (vh) is an L1 hit for 15/16 rows; LDS plane-exchange
//    with per-plane barriers measured ~3-4us SLOWER (R1). Keep dual-load.
//  - forced 8 waves/SIMD + ballot counting REGRESSED (R3). Keep cndmask.
//  - 2-deep pipeline WON ~1.4us (R4). 3-deep REGRESSED ~1.2us (R5, likely
//    VGPR>128 -> occupancy halved). Keep 2-deep.
//  - R6: de-bundled XCD-chunk swizzle only (bijective, 512%8==0): each XCD
//    owns 2 whole batches -> slab-boundary vh refetch and d-seg overlap
//    planes stay XCD-local (L2) instead of cross-XCD (L3).
__global__ __launch_bounds__(THREADS)
void partial_kernel(const float* __restrict__ pred, float* __restrict__ ws)
{
    // bijective XCD swizzle: HW round-robins consecutive blockIdx across 8
    // XCDs; g gives XCD k the contiguous work chunk [k*CHUNK, (k+1)*CHUNK).
    const int bid = (int)blockIdx.x;
    const int g   = (bid & (NXCD - 1)) * CHUNK + (bid >> 3);
    const int b     = g >> 5;          // batch 0..15
    const int rem   = g & 31;
    const int hwblk = rem >> 2;        // row-slab 0..7
    const int seg   = rem & 3;         // d-segment 0..3

    const int tid   = (int)threadIdx.x;
    const int r     = tid >> 5;                // local row 0..15

    const int  h    = hwblk * ROWS + r;
    const bool do_h = (h < DIM - 1);           // h-pair (h,h+1) exists
    const bool do_w = ((tid & 31) != 31);      // w-cross pair exists

    const float4* __restrict__ s4 =
        reinterpret_cast<const float4*>(pred + (size_t)b * VOX);

    const int d0    = seg * DPS;
    const int d_end = (seg == DSEGS - 1) ? (DIM - 1) : (d0 + DPS);

    float cnt_min = 0.f, cnt_max = 0.f, sum_d = 0.f, sum_h = 0.f,
          sum_w = 0.f, sm = 0.f, sm2 = 0.f, les = 0.f;
    const float4 zero4 = { 0.f, 0.f, 0.f, 0.f };

    // element stats + w/h diffs for one float4 (its plane)
    auto process = [&](const float4& v, const float4& vh) {
        const float xs[4] = { v.x, v.y, v.z, v.w };
        #pragma unroll
        for (int j = 0; j < 4; ++j) {
            const float x  = xs[j];
            const float mk = (x > MIN_T) ? 1.0f : 0.0f;
            cnt_min += mk;
            cnt_max += (x > MAX_T)    ? 1.0f : 0.0f;
            les     += (x > LESION_T) ? 1.0f : 0.0f;
            sm      += x * mk;
            sm2     += x * x * mk;
        }
        sum_w += fabsf(v.y - v.x) + fabsf(v.z - v.y) + fabsf(v.w - v.z);
        const float nx = __shfl_down(v.x, 1, 64);   // next float4's .x (same row)
        if (do_w) sum_w += fabsf(nx - v.w);
        if (do_h) sum_h += fabsf(vh.x - v.x) + fabsf(vh.y - v.y)
                         + fabsf(vh.z - v.z) + fabsf(vh.w - v.w);
    };

    // thread owns float4 at (h, w4 = tid&31) on every plane.
    // Pipeline: A = plane d-1, B = plane d, C = prefetch of plane d+1.
    size_t base = (size_t)d0 * PLANE_F4 + hwblk * THREADS + tid;

    float4 vA  = s4[base];
    float4 vAh = do_h ? s4[base + 32] : zero4;
    float4 vB  = s4[base + PLANE_F4];
    float4 vBh = do_h ? s4[base + PLANE_F4 + 32] : zero4;

    // pairs (d-1, d) for d in [d0+1, d_end]; stats for planes d0 .. d_end-1
    #pragma unroll 2
    for (int d = d0 + 1; d <= d_end; ++d) {
        float4 vC = zero4, vCh = zero4;
        if (d < d_end) {                        // uniform branch; no OOB, no waste
            vC  = s4[base + 2 * (size_t)PLANE_F4];
            vCh = do_h ? s4[base + 2 * (size_t)PLANE_F4 + 32] : zero4;
        }
        process(vA, vAh);
        sum_d += fabsf(vB.x - vA.x) + fabsf(vB.y - vA.y)
               + fabsf(vB.z - vA.z) + fabsf(vB.w - vA.w);
        vA = vB; vAh = vBh;
        vB = vC; vBh = vCh;
        base += PLANE_F4;
    }
    if (seg == DSEGS - 1)       // plane 127's element stats (not a d-pair source)
        process(vA, vAh);

    // wave (64-lane) shuffle reduction, then LDS across 8 waves
    float vals[NACC] = { cnt_min, cnt_max, sum_d, sum_h, sum_w, sm, sm2, les };
    #pragma unroll
    for (int vi = 0; vi < NACC; ++vi) {
        float x = vals[vi];
        #pragma unroll
        for (int off = 32; off > 0; off >>= 1)
            x += __shfl_down(x, off, 64);
        vals[vi] = x;
    }

    __shared__ float red[NWAVES][NACC];
    const int wave = tid >> 6;
    const int lane = tid & 63;
    if (lane == 0) {
        #pragma unroll
        for (int vi = 0; vi < NACC; ++vi) red[wave][vi] = vals[vi];
    }
    __syncthreads();
    if (tid < NACC) {
        float t = 0.f;
        #pragma unroll
        for (int w = 0; w < NWAVES; ++w) t += red[w][tid];
        const int slot = b * SLOTS_PER_B + hwblk * DSEGS + seg;
        ws[(size_t)slot * NACC + tid] = t;   // distinct slot: no memset, no atomics
    }
}

__global__ __launch_bounds__(512)
void finalize_kernel(const float* __restrict__ ws, float* __restrict__ out)
{
    const int tid = (int)threadIdx.x;
    const int b   = tid >> 5;      // batch 0..15 (one 32-lane group per batch)
    const int k   = tid & 31;      // slot within batch

    double a[NACC];
    const float* p = ws + ((size_t)(b * SLOTS_PER_B + k)) * NACC;
    #pragma unroll
    for (int vi = 0; vi < NACC; ++vi) a[vi] = (double)p[vi];

    #pragma unroll
    for (int vi = 0; vi < NACC; ++vi) {
        #pragma unroll
        for (int off = 16; off > 0; off >>= 1)
            a[vi] += __shfl_down(a[vi], off, 32);
    }

    __shared__ double bl[NB];
    if (k == 0) {
        const double cnt    = a[0];
        const double cntmax = a[1];
        const double sd     = a[2];
        const double sh     = a[3];
        const double sw     = a[4];
        const double sm     = a[5];
        const double sm2    = a[6];
        const double les    = a[7];

        const double inv_vox = 1.0 / (double)VOX;
        const double act  = cnt    * inv_vox;
        const double high = cntmax * inv_vox;

        double loss = fmax(0.005 - act, 0.0) * 15.0      // W_MIN
                    + fmax(high - 0.03, 0.0) * 5.0;      // W_MAX

        const double grad_den = 127.0 * 128.0 * 128.0;   // diff-array size
        const double avg_grad = (sd + sh + sw) / (3.0 * grad_den);
        if (les > 0.5)
            loss += fmin(avg_grad, 1.0) * 5.0;           // W_CONT

        const double cnt_safe = fmax(cnt, 1.0);
        const double m  = sm / cnt_safe;
        double sq = sm2 - 2.0 * m * sm + m * m * cnt;
        if (sq < 0.0) sq = 0.0;

        const bool gate = (act > 0.001) && (cnt > 1.0);
        if (gate) {
            const double var     = sq / fmax(cnt - 1.0, 1.0);
            const double rel_std = sqrt(var) / (m + 1e-6);
            loss += exp(-5.0 * rel_std) * 7.0;           // W_SIZE
        }
        bl[b] = loss;
    }
    __syncthreads();
    if (tid == 0) {
        double s = 0.0;
        #pragma unroll
        for (int i = 0; i < NB; ++i) s += bl[i];
        out[0] = (float)(s / (double)NB);
    }
}

extern "C" void kernel_launch(void* const* d_in, const int* in_sizes, int n_in,
                              void* d_out, int out_size, void* d_ws, size_t ws_size,
                              hipStream_t stream)
{
    const float* pred = (const float*)d_in[0];
    float* out        = (float*)d_out;
    float* ws         = (float*)d_ws;

    partial_kernel<<<dim3(NBLKS), THREADS, 0, stream>>>(pred, ws);
    finalize_kernel<<<1, 512, 0, stream>>>(ws, out);
}